// Round 1
// baseline (403.395 us; speedup 1.0000x reference)
//
#include <hip/hip_runtime.h>

#define BLOCK 256
#define EPB 64        // batch elements per block
#define LDK 136       // padded row stride in bf16 elements (128 + 8) -> spreads LDS banks, keeps 16B align

typedef __attribute__((ext_vector_type(8))) short short8;   // 8 bf16 = 4 VGPRs (MFMA A/B frag)
typedef __attribute__((ext_vector_type(4))) float f32x4;    // MFMA C/D frag

__device__ __forceinline__ unsigned short f2bf(float f) {
    unsigned u = __float_as_uint(f);
    u += 0x7FFF + ((u >> 16) & 1);    // round-to-nearest-even
    return (unsigned short)(u >> 16);
}

__global__ __launch_bounds__(BLOCK) void mf_fused(
    const int* __restrict__ users, const int* __restrict__ items,
    const float* __restrict__ user_emb, const float* __restrict__ item_emb,
    const float* __restrict__ user_bias, const float* __restrict__ item_bias,
    const float* __restrict__ global_bias,
    const float* __restrict__ w1, const float* __restrict__ b1,
    const float* __restrict__ w2, const float* __restrict__ b2,
    float* __restrict__ out)
{
    __shared__ unsigned short sA[EPB * LDK];   // mlp_in  (bf16) [e][k], k: 0..63 user, 64..127 item
    __shared__ unsigned short sB[128 * LDK];   // W1      (bf16) [h][k]
    __shared__ float sSum[EPB];                // dot + user_bias + item_bias + global_bias + b2
    __shared__ float sB1[128];
    __shared__ float sW2[128];

    const int tid = threadIdx.x;
    const int e0 = blockIdx.x * EPB;

    // ---- stage W1 -> sB as bf16 [h][k] (global read coalesced along k) ----
    {
        const int c = tid & 31;      // float4 chunk within a 128-float row
        const int h0 = tid >> 5;     // 0..7
        #pragma unroll
        for (int it = 0; it < 16; ++it) {
            const int h = h0 + it * 8;
            const float4 wv = *(const float4*)(w1 + h * 128 + c * 4);
            ushort4 pk;
            pk.x = f2bf(wv.x); pk.y = f2bf(wv.y); pk.z = f2bf(wv.z); pk.w = f2bf(wv.w);
            *(ushort4*)&sB[h * LDK + c * 4] = pk;
        }
    }
    if (tid < 128) { sB1[tid] = b1[tid]; sW2[tid] = w2[tid]; }

    // ---- gather u/v rows -> sA (bf16); fp32 dot + biases -> sSum ----
    {
        const int c = tid & 15;      // float4 chunk within a 64-float row
        const int er = tid >> 4;     // 0..15
        int uid[4], iid[4];
        #pragma unroll
        for (int it = 0; it < 4; ++it) {
            uid[it] = users[e0 + er + it * 16];
            iid[it] = items[e0 + er + it * 16];
        }
        float4 u4[4], v4[4];
        #pragma unroll
        for (int it = 0; it < 4; ++it) {
            u4[it] = *(const float4*)(user_emb + (size_t)uid[it] * 64 + c * 4);
            v4[it] = *(const float4*)(item_emb + (size_t)iid[it] * 64 + c * 4);
        }
        const float gb = global_bias[0] + b2[0];
        #pragma unroll
        for (int it = 0; it < 4; ++it) {
            const int eloc = er + it * 16;
            ushort4 pu, pv;
            pu.x = f2bf(u4[it].x); pu.y = f2bf(u4[it].y);
            pu.z = f2bf(u4[it].z); pu.w = f2bf(u4[it].w);
            pv.x = f2bf(v4[it].x); pv.y = f2bf(v4[it].y);
            pv.z = f2bf(v4[it].z); pv.w = f2bf(v4[it].w);
            *(ushort4*)&sA[eloc * LDK + c * 4]      = pu;
            *(ushort4*)&sA[eloc * LDK + 64 + c * 4] = pv;
            float p = u4[it].x * v4[it].x + u4[it].y * v4[it].y
                    + u4[it].z * v4[it].z + u4[it].w * v4[it].w;
            p += __shfl_xor(p, 1);
            p += __shfl_xor(p, 2);
            p += __shfl_xor(p, 4);
            p += __shfl_xor(p, 8);
            if (c == 0)
                sSum[eloc] = p + user_bias[uid[it]] + item_bias[iid[it]] + gb;
        }
    }

    __syncthreads();

    // ---- MFMA: one wave = 16 elements x 128 hidden (8 n-tiles x 4 k-steps) ----
    const int lane = tid & 63;
    const int wv   = tid >> 6;     // wave 0..3
    const int quad = lane >> 4;    // 0..3
    const int nidx = lane & 15;
    const int eRow = wv * 16;

    f32x4 acc[8];
    #pragma unroll
    for (int nt = 0; nt < 8; ++nt) acc[nt] = (f32x4){0.f, 0.f, 0.f, 0.f};

    #pragma unroll
    for (int kk = 0; kk < 4; ++kk) {
        // A frag: A[m=lane&15][k=quad*8+j]
        const short8 a = *(const short8*)&sA[(eRow + nidx) * LDK + kk * 32 + quad * 8];
        #pragma unroll
        for (int nt = 0; nt < 8; ++nt) {
            // B frag: B[k=quad*8+j][n=lane&15], B = W1^T so read sB[h][k]
            const short8 b = *(const short8*)&sB[(nt * 16 + nidx) * LDK + kk * 32 + quad * 8];
            acc[nt] = __builtin_amdgcn_mfma_f32_16x16x32_bf16(a, b, acc[nt], 0, 0, 0);
        }
    }

    // ---- epilogue: h = relu(acc + b1); partial = h * w2; reduce over 16 n-lanes ----
    float p0 = 0.f, p1 = 0.f, p2 = 0.f, p3 = 0.f;
    #pragma unroll
    for (int nt = 0; nt < 8; ++nt) {
        const int h = nt * 16 + nidx;
        const float b1v = sB1[h];
        const float w2v = sW2[h];
        p0 += fmaxf(acc[nt][0] + b1v, 0.f) * w2v;
        p1 += fmaxf(acc[nt][1] + b1v, 0.f) * w2v;
        p2 += fmaxf(acc[nt][2] + b1v, 0.f) * w2v;
        p3 += fmaxf(acc[nt][3] + b1v, 0.f) * w2v;
    }
    #define RED16(p) { p += __shfl_xor(p, 1); p += __shfl_xor(p, 2); \
                       p += __shfl_xor(p, 4); p += __shfl_xor(p, 8); }
    RED16(p0) RED16(p1) RED16(p2) RED16(p3)

    if (nidx == 0) {
        // D row m = quad*4 + r  ->  element eRow + quad*4 + r
        const int eb = eRow + quad * 4;
        float4 o;
        o.x = p0 + sSum[eb + 0];
        o.y = p1 + sSum[eb + 1];
        o.z = p2 + sSum[eb + 2];
        o.w = p3 + sSum[eb + 3];
        *(float4*)(out + e0 + eb) = o;
    }
}

extern "C" void kernel_launch(void* const* d_in, const int* in_sizes, int n_in,
                              void* d_out, int out_size, void* d_ws, size_t ws_size,
                              hipStream_t stream) {
    const int*   users       = (const int*)d_in[0];
    const int*   items       = (const int*)d_in[1];
    const float* user_emb    = (const float*)d_in[2];
    const float* item_emb    = (const float*)d_in[3];
    const float* user_bias   = (const float*)d_in[4];
    const float* item_bias   = (const float*)d_in[5];
    const float* global_bias = (const float*)d_in[6];
    const float* w1          = (const float*)d_in[7];
    const float* b1          = (const float*)d_in[8];
    const float* w2          = (const float*)d_in[9];
    const float* b2          = (const float*)d_in[10];
    float* out = (float*)d_out;

    const int batch = in_sizes[0];          // 16384
    const int grid = batch / EPB;           // 256 blocks
    mf_fused<<<grid, BLOCK, 0, stream>>>(users, items, user_emb, item_emb,
        user_bias, item_bias, global_bias, w1, b1, w2, b2, out);
}

// Round 2
// 400.726 us; speedup vs baseline: 1.0067x; 1.0067x over previous
//
#include <hip/hip_runtime.h>

#define BLOCK 256
#define EPB 32        // batch elements per block
#define LDK 136       // padded LDS row stride in bf16 elements (128+8): breaks the
                      // 16-way bank conflict of a 256B stride, keeps 16B alignment

typedef __attribute__((ext_vector_type(8))) short short8;   // 8 bf16 = 4 VGPRs (MFMA A/B frag)
typedef __attribute__((ext_vector_type(4))) float f32x4;    // MFMA C/D frag

__device__ __forceinline__ unsigned short f2bf(float f) {
    unsigned u = __float_as_uint(f);
    u += 0x7FFF + ((u >> 16) & 1);    // round-to-nearest-even
    return (unsigned short)(u >> 16);
}

// grid=512 (2 blocks/CU co-resident; LDS ~45KB/block). One block: 32 batch
// elements. Wave w: m-rows (w&1)*16..+16, n-half (w>>1)*64..+64 of HIDDEN.
__global__ __launch_bounds__(BLOCK, 2) void mf_fused(
    const int* __restrict__ users, const int* __restrict__ items,
    const float* __restrict__ user_emb, const float* __restrict__ item_emb,
    const float* __restrict__ user_bias, const float* __restrict__ item_bias,
    const float* __restrict__ global_bias,
    const float* __restrict__ w1, const float* __restrict__ b1,
    const float* __restrict__ w2, const float* __restrict__ b2,
    float* __restrict__ out)
{
    __shared__ unsigned short sA[EPB * LDK];   // mlp_in (bf16) [e][k], k: 0..63 user, 64..127 item
    __shared__ unsigned short sB[128 * LDK];   // W1     (bf16) [h][k]
    __shared__ float sSum[EPB];                // dot + user_bias + item_bias + global_bias + b2
    __shared__ float sP[2][EPB];               // per-n-half MLP partials
    __shared__ float sB1[128];
    __shared__ float sW2[128];

    const int tid = threadIdx.x;
    const int e0 = blockIdx.x * EPB;

    // ---- indices first: longest dependence chain (idx -> gather) ----
    const int c  = tid & 15;      // float4 chunk within a 64-float row
    const int er = tid >> 4;      // 0..15 -> elements er and er+16
    const int uid_a = users[e0 + er];
    const int uid_b = users[e0 + er + 16];
    const int iid_a = items[e0 + er];
    const int iid_b = items[e0 + er + 16];

    if (tid < 128) { sB1[tid] = b1[tid]; sW2[tid] = w2[tid]; }

    // ---- stage W1 -> sB as bf16 [h][k] (independent L2 loads: fill idx-latency) ----
    {
        const int c2 = tid & 31;     // float4 chunk within a 128-float row
        const int h0 = tid >> 5;     // 0..7
        #pragma unroll
        for (int it = 0; it < 16; ++it) {
            const int h = h0 + it * 8;
            const float4 wv = *(const float4*)(w1 + h * 128 + c2 * 4);
            ushort4 pk;
            pk.x = f2bf(wv.x); pk.y = f2bf(wv.y); pk.z = f2bf(wv.z); pk.w = f2bf(wv.w);
            *(ushort4*)&sB[h * LDK + c2 * 4] = pk;
        }
    }

    // ---- gather u/v rows -> sA (bf16); fp32 dot + biases -> sSum ----
    {
        const float4 ua = *(const float4*)(user_emb + (size_t)uid_a * 64 + c * 4);
        const float4 va = *(const float4*)(item_emb + (size_t)iid_a * 64 + c * 4);
        const float4 ub = *(const float4*)(user_emb + (size_t)uid_b * 64 + c * 4);
        const float4 vb = *(const float4*)(item_emb + (size_t)iid_b * 64 + c * 4);
        const float gb = global_bias[0] + b2[0];
        const float uba = user_bias[uid_a], ubb = user_bias[uid_b];
        const float iba = item_bias[iid_a], ibb = item_bias[iid_b];

        ushort4 pk;
        pk.x = f2bf(ua.x); pk.y = f2bf(ua.y); pk.z = f2bf(ua.z); pk.w = f2bf(ua.w);
        *(ushort4*)&sA[er * LDK + c * 4] = pk;
        pk.x = f2bf(va.x); pk.y = f2bf(va.y); pk.z = f2bf(va.z); pk.w = f2bf(va.w);
        *(ushort4*)&sA[er * LDK + 64 + c * 4] = pk;
        pk.x = f2bf(ub.x); pk.y = f2bf(ub.y); pk.z = f2bf(ub.z); pk.w = f2bf(ub.w);
        *(ushort4*)&sA[(er + 16) * LDK + c * 4] = pk;
        pk.x = f2bf(vb.x); pk.y = f2bf(vb.y); pk.z = f2bf(vb.z); pk.w = f2bf(vb.w);
        *(ushort4*)&sA[(er + 16) * LDK + 64 + c * 4] = pk;

        float pa = ua.x * va.x + ua.y * va.y + ua.z * va.z + ua.w * va.w;
        float pb = ub.x * vb.x + ub.y * vb.y + ub.z * vb.z + ub.w * vb.w;
        #define RED16(p) { p += __shfl_xor(p, 1); p += __shfl_xor(p, 2); \
                           p += __shfl_xor(p, 4); p += __shfl_xor(p, 8); }
        RED16(pa) RED16(pb)
        if (c == 0) {
            sSum[er]      = pa + uba + iba + gb;
            sSum[er + 16] = pb + ubb + ibb + gb;
        }
    }

    __syncthreads();

    // ---- MFMA: wave = 16 elements x 64 hidden (4 n-tiles x 4 k-steps) ----
    const int lane  = tid & 63;
    const int wv    = tid >> 6;        // 0..3
    const int quad  = lane >> 4;       // 0..3
    const int nidx  = lane & 15;
    const int mrow0 = (wv & 1) * 16;   // element-row base
    const int nhalf = wv >> 1;         // hidden half 0/1
    const int hbase = nhalf * 64;

    f32x4 acc[4];
    #pragma unroll
    for (int nt = 0; nt < 4; ++nt) acc[nt] = (f32x4){0.f, 0.f, 0.f, 0.f};

    #pragma unroll
    for (int kk = 0; kk < 4; ++kk) {
        // A frag: A[m=lane&15][k=quad*8+j]
        const short8 a = *(const short8*)&sA[(mrow0 + nidx) * LDK + kk * 32 + quad * 8];
        #pragma unroll
        for (int nt = 0; nt < 4; ++nt) {
            const short8 b = *(const short8*)&sB[(hbase + nt * 16 + nidx) * LDK + kk * 32 + quad * 8];
            acc[nt] = __builtin_amdgcn_mfma_f32_16x16x32_bf16(a, b, acc[nt], 0, 0, 0);
        }
    }

    // ---- epilogue: relu + w2 dot over this wave's 64 hidden; reduce over n-lanes ----
    float p0 = 0.f, p1 = 0.f, p2 = 0.f, p3 = 0.f;
    #pragma unroll
    for (int nt = 0; nt < 4; ++nt) {
        const int h = hbase + nt * 16 + nidx;
        const float b1v = sB1[h];
        const float w2v = sW2[h];
        p0 += fmaxf(acc[nt][0] + b1v, 0.f) * w2v;
        p1 += fmaxf(acc[nt][1] + b1v, 0.f) * w2v;
        p2 += fmaxf(acc[nt][2] + b1v, 0.f) * w2v;
        p3 += fmaxf(acc[nt][3] + b1v, 0.f) * w2v;
    }
    RED16(p0) RED16(p1) RED16(p2) RED16(p3)

    if (nidx == 0) {
        const int eb = mrow0 + quad * 4;    // D row m = quad*4 + r
        sP[nhalf][eb + 0] = p0;
        sP[nhalf][eb + 1] = p1;
        sP[nhalf][eb + 2] = p2;
        sP[nhalf][eb + 3] = p3;
    }
    __syncthreads();

    if (tid < EPB)
        out[e0 + tid] = sSum[tid] + sP[0][tid] + sP[1][tid];
}

extern "C" void kernel_launch(void* const* d_in, const int* in_sizes, int n_in,
                              void* d_out, int out_size, void* d_ws, size_t ws_size,
                              hipStream_t stream) {
    const int*   users       = (const int*)d_in[0];
    const int*   items       = (const int*)d_in[1];
    const float* user_emb    = (const float*)d_in[2];
    const float* item_emb    = (const float*)d_in[3];
    const float* user_bias   = (const float*)d_in[4];
    const float* item_bias   = (const float*)d_in[5];
    const float* global_bias = (const float*)d_in[6];
    const float* w1          = (const float*)d_in[7];
    const float* b1          = (const float*)d_in[8];
    const float* w2          = (const float*)d_in[9];
    const float* b2          = (const float*)d_in[10];
    float* out = (float*)d_out;

    const int batch = in_sizes[0];          // 16384
    const int grid = batch / EPB;           // 512 blocks -> 2 blocks/CU
    mf_fused<<<grid, BLOCK, 0, stream>>>(users, items, user_emb, item_emb,
        user_bias, item_bias, global_bias, w1, b1, w2, b2, out);
}